// Round 11
// baseline (314.789 us; speedup 1.0000x reference)
//
#include <hip/hip_runtime.h>
#include <hip/hip_bf16.h>

#define N_ROWS 262144
#define D_IN 162
#define K_DIM 30
#define ROWS 32          // rows per tile; each block pipelines TWO tiles
#define NTHR 512

using bf16_t = __hip_bfloat16;
typedef __attribute__((ext_vector_type(8))) short bf16x8;
typedef __attribute__((ext_vector_type(4))) float f32x4;

// byte offset into a swizzled LDS tile: row stride 512 B, col in bf16 elems.
__device__ __forceinline__ int swz_byte(int row, int col) {
  int b = (row << 9) + (col << 1);
  return b ^ ((row & 7) << 4);
}

__device__ __forceinline__ uint32_t bf16b(float x) {
  return (uint32_t)__builtin_bit_cast(unsigned short, __float2bfloat16(x));
}
__device__ __forceinline__ uint32_t pack2(float lo, float hi) {
  return bf16b(lo) | (bf16b(hi) << 16);
}
__device__ __forceinline__ float unpk_lo(uint32_t p) {
  return __bfloat162float(__builtin_bit_cast(__hip_bfloat16, (unsigned short)(p & 0xffff)));
}
__device__ __forceinline__ float unpk_hi(uint32_t p) {
  return __bfloat162float(__builtin_bit_cast(__hip_bfloat16, (unsigned short)(p >> 16)));
}

__device__ __forceinline__ float fexp2(float x) { return __builtin_amdgcn_exp2f(x); }
__device__ __forceinline__ float flog2(float x) { return __builtin_amdgcn_logf(x); }
__device__ __forceinline__ float frcp (float x) { return __builtin_amdgcn_rcpf(x); }

__device__ __forceinline__ float sp_fast(float x) {        // softplus
  float e = fexp2(fabsf(x) * -1.44269504f);
  return fmaxf(x, 0.f) + 0.69314718f * flog2(1.f + e);
}
__device__ __forceinline__ float sigmoid_fast(float x) {
  return frcp(1.f + fexp2(x * -1.44269504f));
}

// ---------------- weight packing: fp32 [K][N] -> bf16 [kb][Np][32] ------------
__global__ void pack_b_kernel(const float* __restrict__ src, bf16_t* __restrict__ dst,
                              int K, int N, int Np, int KB) {
  int idx = blockIdx.x * 256 + threadIdx.x;
  int total = KB * Np * 32;
  if (idx >= total) return;
  int ks = idx & 31;
  int n  = (idx >> 5) % Np;
  int kb = idx / (32 * Np);
  int k  = kb * 32 + ks;
  float v = (k < K && n < N) ? src[k * N + n] : 0.f;
  dst[idx] = __float2bfloat16(v);
}

// Wa/Wb interleaved: out-col 2j = Wa[:,j], 2j+1 = Wb[:,j]
__global__ void pack_ab_kernel(const float* __restrict__ Wa, const float* __restrict__ Wb,
                               bf16_t* __restrict__ dst) {
  int idx = blockIdx.x * 256 + threadIdx.x;
  if (idx >= 8 * 64 * 32) return;
  int ks = idx & 31;
  int n  = (idx >> 5) & 63;
  int kb = idx >> 11;
  int k  = kb * 32 + ks;
  int j = n >> 1, s = n & 1;
  float v = (j < K_DIM) ? (s ? Wb[k * K_DIM + j] : Wa[k * K_DIM + j]) : 0.f;
  dst[idx] = __float2bfloat16(v);
}

// ---------------- weight fragment load ----------------------------------------
template<int NP, int NMO>
__device__ __forceinline__ void wload(const bf16_t* __restrict__ Wp, int kb, int ocBase,
                                      int lr, int lg, bf16x8 (&out)[NMO]) {
#pragma unroll
  for (int mo = 0; mo < NMO; ++mo)
    out[mo] = *reinterpret_cast<const bf16x8*>(
        Wp + ((kb * NP + ocBase + 16 * mo + lr) << 5) + 8 * lg);
}

// ---------------- swapped-operand GEMM ----------------------------------------
template<int KB, int NP, int NMO, int NR>
__device__ __forceinline__ void gemm_direct(const uint8_t* lds, int srcOff,
                                            const bf16_t* __restrict__ Wp, int ocBase,
                                            int lr, int lg, f32x4 (&acc)[NMO][NR]) {
  int bE[NR], bO[NR];   // even/odd-kb bases (128B pair-steps commute with row-XOR)
#pragma unroll
  for (int nr = 0; nr < NR; ++nr) {
    bE[nr] = srcOff + swz_byte(16 * nr + lr, 8 * lg);
    bO[nr] = srcOff + swz_byte(16 * nr + lr, 32 + 8 * lg);
  }
#pragma unroll
  for (int kb = 0; kb < KB; ++kb) {
    bf16x8 wf[NMO];
    wload<NP, NMO>(Wp, kb, ocBase, lr, lg, wf);
    bf16x8 hf[NR];
#pragma unroll
    for (int nr = 0; nr < NR; ++nr) {
      int base = (kb & 1) ? bO[nr] : bE[nr];
      hf[nr] = *reinterpret_cast<const bf16x8*>(lds + base + (kb >> 1) * 128);
    }
#pragma unroll
    for (int mo = 0; mo < NMO; ++mo)
#pragma unroll
      for (int nr = 0; nr < NR; ++nr)
        acc[mo][nr] = __builtin_amdgcn_mfma_f32_16x16x32_bf16(wf[mo], hf[nr], acc[mo][nr], 0, 0, 0);
  }
}

template<int NMO, int NR>
__device__ __forceinline__ void acc_bias_init(const float* __restrict__ bias, int ocBase,
                                              int lg, f32x4 (&acc)[NMO][NR]) {
#pragma unroll
  for (int mo = 0; mo < NMO; ++mo) {
    float4 bv = *reinterpret_cast<const float4*>(bias + ocBase + 16 * mo + 4 * lg);
    f32x4 t = {bv.x, bv.y, bv.z, bv.w};
#pragma unroll
    for (int nr = 0; nr < NR; ++nr) acc[mo][nr] = t;
  }
}

// relu -> packed bf16x4 -> one ds_write_b64 per fragment
template<int NMO, int NR>
__device__ __forceinline__ void epi_relu_store(uint8_t* lds, int dstOff, int ocBase,
                                               int lr, int lg, f32x4 (&acc)[NMO][NR]) {
#pragma unroll
  for (int mo = 0; mo < NMO; ++mo)
#pragma unroll
    for (int nr = 0; nr < NR; ++nr) {
      int row = 16 * nr + lr;
      int col = ocBase + 16 * mo + 4 * lg;
      float x0 = fmaxf(acc[mo][nr][0], 0.f), x1 = fmaxf(acc[mo][nr][1], 0.f);
      float x2 = fmaxf(acc[mo][nr][2], 0.f), x3 = fmaxf(acc[mo][nr][3], 0.f);
      uint2 p; p.x = pack2(x0, x1); p.y = pack2(x2, x3);
      *reinterpret_cast<uint2*>(lds + dstOff + swz_byte(row, col)) = p;
    }
}

// ---------------- fused scan + fragment build ---------------------------------
template<int LG>
__device__ __forceinline__ bf16x8 scan_frag(const float* __restrict__ vrow,
                                            uint8_t* __restrict__ piPair) {
  float ex = 1.f, hold = 0.f;
  uint32_t pk0 = 0, pk1 = 0, pk2 = 0, pk3 = 0;
#pragma unroll
  for (int j = 0; j < 32; ++j) {
    float pi;
    if (j < K_DIM - 1)       { float vj = vrow[j]; pi = vj * ex; ex *= (1.f - vj); }
    else if (j == K_DIM - 1)   pi = ex;      // v_K forced to 1
    else                       pi = 0.f;     // pad K->32
    if (j & 1) {
      uint32_t p = pack2(hold, pi);
      if (piPair != nullptr && j < K_DIM)
        *reinterpret_cast<uint32_t*>(piPair + (j - 1) * 2) = p;
      if (j >= 8 * LG && j < 8 * LG + 8) {
        switch ((j - 8 * LG) >> 1) {
          case 0: pk0 = p; break; case 1: pk1 = p; break;
          case 2: pk2 = p; break; default: pk3 = p;
        }
      }
    } else hold = pi;
  }
  uint4 t = make_uint4(pk0, pk1, pk2, pk3);
  return __builtin_bit_cast(bf16x8, t);
}

// ---------------- phase helpers (per tile) ------------------------------------
// P0 stage: 16 threads/row
__device__ __forceinline__ void p0_read(const float* __restrict__ Yh, int r0, int tid,
                                        float2 (&sv)[6]) {
  int srow = tid >> 4, s16 = tid & 15;
  const float2* src = reinterpret_cast<const float2*>(Yh + (size_t)(r0 + srow) * D_IN);
#pragma unroll
  for (int it = 0; it < 6; ++it) {
    int f2 = s16 + it * 16;
    if (f2 < 81) sv[it] = src[f2];
  }
}
__device__ __forceinline__ void p0_write(uint8_t* __restrict__ buf, int tid,
                                         const float2 (&sv)[6]) {
  int srow = tid >> 4, s16 = tid & 15;
#pragma unroll
  for (int it = 0; it < 6; ++it) {
    int f2 = s16 + it * 16;                 // 0..95: data + zero pad to col 191
    uint32_t p = (f2 < 81) ? pack2(sv[it].x, sv[it].y) : 0u;
    *reinterpret_cast<uint32_t*>(buf + swz_byte(srow, f2 * 2)) = p;
  }
}

// P3 heads (waves 0..3): gemm + softplus + Kumaraswamy v; defers alpha/beta in regs
__device__ __forceinline__ void heads_read(const uint8_t* __restrict__ buf,
                                           const bf16_t* __restrict__ Wpab,
                                           const float* __restrict__ ba,
                                           const float* __restrict__ bb,
                                           const float* __restrict__ u,
                                           int w, int lr, int lg,
                                           float (&vv)[2][2], float (&rA)[2][2],
                                           float (&rB)[2][2]) {
  if (w >= 4) return;
  int j0 = 8 * w + 2 * lg;
  bool jv = (j0 < K_DIM);
  float ba0 = jv ? ba[j0] : 0.f,     bb0 = jv ? bb[j0] : 0.f;
  float ba1 = jv ? ba[j0 + 1] : 0.f, bb1 = jv ? bb[j0 + 1] : 0.f;
  f32x4 acc[1][2];
  f32x4 binit = {ba0, bb0, ba1, bb1};
  acc[0][0] = binit; acc[0][1] = binit;
  gemm_direct<8, 64, 1, 2>(buf, 0, Wpab, 16 * w, lr, lg, acc);
  float uu  = u[0] * 0.98f + 0.01f;
  float l2u = flog2(uu);
#pragma unroll
  for (int nr = 0; nr < 2; ++nr) {
    float a0  = sp_fast(acc[0][nr][0]) + 1e-4f;
    float b0v = sp_fast(acc[0][nr][1]) + 1e-4f;
    float a1  = sp_fast(acc[0][nr][2]) + 1e-4f;
    float b1v = sp_fast(acc[0][nr][3]) + 1e-4f;
    rA[nr][0] = a0; rB[nr][0] = b0v;
    rA[nr][1] = a1; rB[nr][1] = b1v;
    float t0 = fexp2(l2u * frcp(b0v));
    vv[nr][0] = fexp2(flog2(1.f - t0) * frcp(a0));
    float t1 = fexp2(l2u * frcp(b1v));
    vv[nr][1] = fexp2(flog2(1.f - t1) * frcp(a1));
  }
}
__device__ __forceinline__ void heads_write(uint8_t* __restrict__ buf, int w, int lr,
                                            int lg, const float (&vv)[2][2]) {
  if (w >= 4) return;
  int j0 = 8 * w + 2 * lg;
  if (j0 >= K_DIM) return;
  float* vbuf = reinterpret_cast<float*>(buf);     // fp32 [32][33] over dead tile
#pragma unroll
  for (int nr = 0; nr < 2; ++nr) {
    int row = 16 * nr + lr;
    if (j0 < K_DIM - 1)     vbuf[row * 33 + j0]     = vv[nr][0];
    if (j0 + 1 < K_DIM - 1) vbuf[row * 33 + j0 + 1] = vv[nr][1];
  }
}

// P4 scan-fused GEMM4 read: pi fragments + piT write (w0/lg0) + MFMA into acc
__device__ __forceinline__ void g4_read(uint8_t* __restrict__ buf,
                                        uint8_t* __restrict__ piT,
                                        const bf16_t* __restrict__ Wpd1,
                                        const float* __restrict__ bd1,
                                        int w, int lr, int lg, f32x4 (&acc)[2][2]) {
  bf16x8 pf[2];
  const float* vb = reinterpret_cast<const float*>(buf);
#pragma unroll
  for (int nr = 0; nr < 2; ++nr) {
    int row = 16 * nr + lr;
    const float* vrow = vb + row * 33;
    uint8_t* po = (w == 0) ? (piT + row * 80) : nullptr;   // lg==0 path only
    if      (lg == 0) pf[nr] = scan_frag<0>(vrow, po);
    else if (lg == 1) pf[nr] = scan_frag<1>(vrow, nullptr);
    else if (lg == 2) pf[nr] = scan_frag<2>(vrow, nullptr);
    else              pf[nr] = scan_frag<3>(vrow, nullptr);
  }
  acc_bias_init<2, 2>(bd1, w * 32, lg, acc);
  bf16x8 w4[2];
  wload<256, 2>(Wpd1, 0, w * 32, lr, lg, w4);
#pragma unroll
  for (int mo = 0; mo < 2; ++mo)
#pragma unroll
    for (int nr = 0; nr < 2; ++nr)
      acc[mo][nr] = __builtin_amdgcn_mfma_f32_16x16x32_bf16(w4[mo], pf[nr], acc[mo][nr], 0, 0, 0);
}

// P5 GEMM5 (waves 0..5)
__device__ __forceinline__ void g5_read(const uint8_t* __restrict__ buf,
                                        const bf16_t* __restrict__ Wpd2,
                                        const float* __restrict__ bd2,
                                        int w, int lr, int lg, f32x4 (&acc)[2][2]) {
  if (w >= 6) return;
#pragma unroll
  for (int mo = 0; mo < 2; ++mo) {
    int col0 = 32 * w + 16 * mo + 4 * lg;
    f32x4 t;
#pragma unroll
    for (int i = 0; i < 4; ++i) t[i] = (col0 + i < D_IN) ? bd2[col0 + i] : 0.f;
#pragma unroll
    for (int nr = 0; nr < 2; ++nr) acc[mo][nr] = t;
  }
  gemm_direct<8, 192, 2, 2>(buf, 0, Wpd2, 32 * w, lr, lg, acc);
}
__device__ __forceinline__ void g5_write(float* __restrict__ outRecon, int r0,
                                         int w, int lr, int lg, f32x4 (&acc)[2][2]) {
  if (w >= 6) return;
#pragma unroll
  for (int mo = 0; mo < 2; ++mo) {
    int col0 = 32 * w + 16 * mo + 4 * lg;
#pragma unroll
    for (int nr = 0; nr < 2; ++nr) {
      int row = 16 * nr + lr;
      float s0 = sigmoid_fast(acc[mo][nr][0]);
      float s1 = sigmoid_fast(acc[mo][nr][1]);
      float s2 = sigmoid_fast(acc[mo][nr][2]);
      float s3 = sigmoid_fast(acc[mo][nr][3]);
      float* dst = outRecon + (size_t)(r0 + row) * D_IN + col0;
      if (col0 < D_IN)     *reinterpret_cast<float2*>(dst)     = make_float2(s0, s1);
      if (col0 + 2 < D_IN) *reinterpret_cast<float2*>(dst + 2) = make_float2(s2, s3);
    }
  }
}
__device__ __forceinline__ void ab_store(float* __restrict__ outAlpha,
                                         float* __restrict__ outBeta, int r0,
                                         int w, int lr, int lg,
                                         const float (&rA)[2][2], const float (&rB)[2][2]) {
  if (w >= 4) return;
  int j0 = 8 * w + 2 * lg;
  if (j0 >= K_DIM) return;
#pragma unroll
  for (int nr = 0; nr < 2; ++nr) {
    int row = 16 * nr + lr;
    size_t base = (size_t)(r0 + row) * K_DIM + j0;
    *reinterpret_cast<float2*>(outAlpha + base) = make_float2(rA[nr][0], rA[nr][1]);
    *reinterpret_cast<float2*>(outBeta  + base) = make_float2(rB[nr][0], rB[nr][1]);
  }
}
__device__ __forceinline__ void pi_store(float* __restrict__ outPi,
                                         const uint8_t* __restrict__ piT, int r0, int tid) {
  if (tid >= 128) return;
  int row = tid >> 2, l4 = tid & 3;
#pragma unroll
  for (int it = 0; it < 4; ++it) {
    int f2 = l4 + it * 4;
    if (f2 < 15) {
      uint32_t pp = *reinterpret_cast<const uint32_t*>(piT + row * 80 + f2 * 4);
      *reinterpret_cast<float2*>(outPi + (size_t)(r0 + row) * K_DIM + f2 * 2) =
          make_float2(unpk_lo(pp), unpk_hi(pp));
    }
  }
}

// ---------------- fused forward: two-tile phase-staggered pipeline ------------
// Block handles tiles A (r0) and B (r0+32), B one phase behind A. Every region:
// {A.phase[r].reads ; B.phase[r-1].reads} barrier {writes} barrier.
// LDS: bufA [0,16K) in-place Yh->h1->h2->vbuf->d; bufB [16K,32K) same;
// piTA [32768,35328), piTB [35328,37888).
__launch_bounds__(NTHR, 4)
__global__ void usdn_fused(const float* __restrict__ Yh, const float* __restrict__ u,
                           const float* __restrict__ b1, const float* __restrict__ b2,
                           const float* __restrict__ ba, const float* __restrict__ bb,
                           const float* __restrict__ bd1, const float* __restrict__ bd2,
                           const bf16_t* __restrict__ Wp1, const bf16_t* __restrict__ Wp2,
                           const bf16_t* __restrict__ Wpab, const bf16_t* __restrict__ Wpd1,
                           const bf16_t* __restrict__ Wpd2,
                           float* __restrict__ outRecon, float* __restrict__ outAlpha,
                           float* __restrict__ outBeta, float* __restrict__ outPi) {
  __shared__ __align__(16) uint8_t lds[37888];
  uint8_t* bufA = lds;
  uint8_t* bufB = lds + 16384;
  uint8_t* piTA = lds + 32768;
  uint8_t* piTB = lds + 35328;

  const int tid = threadIdx.x;
  const int w  = tid >> 6;          // 0..7
  const int l  = tid & 63;
  const int lr = l & 15;
  const int lg = l >> 4;
  const int r0A = blockIdx.x * (2 * ROWS);
  const int r0B = r0A + ROWS;

  float rAA[2][2], rBA[2][2];       // deferred alpha/beta, tile A
  float rAB[2][2], rBB[2][2];       // tile B

  // ---- r0: A.stage
  {
    float2 svA[6];
    p0_read(Yh, r0A, tid, svA);
    p0_write(bufA, tid, svA);
  }
  __syncthreads();                                   // B1

  // ---- r1: A.G1 | B.stage
  {
    float2 svB[6];
    p0_read(Yh, r0B, tid, svB);                      // issue B loads early
    f32x4 acc[2][2];
    acc_bias_init<2, 2>(b1, w * 32, lg, acc);
    gemm_direct<6, 256, 2, 2>(bufA, 0, Wp1, w * 32, lr, lg, acc);
    __syncthreads();                                 // B2 (Yh_A reads done)
    p0_write(bufB, tid, svB);
    epi_relu_store<2, 2>(bufA, 0, w * 32, lr, lg, acc);
  }
  __syncthreads();                                   // B3

  // ---- r2: A.G2 | B.G1
  {
    f32x4 accA[2][2];
    acc_bias_init<2, 2>(b2, w * 32, lg, accA);
    gemm_direct<8, 256, 2, 2>(bufA, 0, Wp2, w * 32, lr, lg, accA);
    f32x4 accB[2][2];
    acc_bias_init<2, 2>(b1, w * 32, lg, accB);
    gemm_direct<6, 256, 2, 2>(bufB, 0, Wp1, w * 32, lr, lg, accB);
    __syncthreads();                                 // B4
    epi_relu_store<2, 2>(bufA, 0, w * 32, lr, lg, accA);
    epi_relu_store<2, 2>(bufB, 0, w * 32, lr, lg, accB);
  }
  __syncthreads();                                   // B5

  // ---- r3: A.heads | B.G2
  {
    float vvA[2][2];
    heads_read(bufA, Wpab, ba, bb, u, w, lr, lg, vvA, rAA, rBA);
    f32x4 accB[2][2];
    acc_bias_init<2, 2>(b2, w * 32, lg, accB);
    gemm_direct<8, 256, 2, 2>(bufB, 0, Wp2, w * 32, lr, lg, accB);
    __syncthreads();                                 // B6
    heads_write(bufA, w, lr, lg, vvA);
    epi_relu_store<2, 2>(bufB, 0, w * 32, lr, lg, accB);
  }
  __syncthreads();                                   // B7

  // ---- r4: A.G4(scan) | B.heads
  {
    f32x4 accA[2][2];
    g4_read(bufA, piTA, Wpd1, bd1, w, lr, lg, accA);
    float vvB[2][2];
    heads_read(bufB, Wpab, ba, bb, u, w, lr, lg, vvB, rAB, rBB);
    __syncthreads();                                 // B8
    epi_relu_store<2, 2>(bufA, 0, w * 32, lr, lg, accA);
    heads_write(bufB, w, lr, lg, vvB);
  }
  __syncthreads();                                   // B9

  // ---- r5: A.G5 | B.G4(scan)
  {
    f32x4 accA[2][2];
    g5_read(bufA, Wpd2, bd2, w, lr, lg, accA);
    f32x4 accB[2][2];
    g4_read(bufB, piTB, Wpd1, bd1, w, lr, lg, accB);
    __syncthreads();                                 // B10
    g5_write(outRecon, r0A, w, lr, lg, accA);
    ab_store(outAlpha, outBeta, r0A, w, lr, lg, rAA, rBA);
    pi_store(outPi, piTA, r0A, tid);
    epi_relu_store<2, 2>(bufB, 0, w * 32, lr, lg, accB);
  }
  __syncthreads();                                   // B11

  // ---- r6: B.G5 + B stores
  {
    f32x4 accB[2][2];
    g5_read(bufB, Wpd2, bd2, w, lr, lg, accB);
    g5_write(outRecon, r0B, w, lr, lg, accB);
    ab_store(outAlpha, outBeta, r0B, w, lr, lg, rAB, rBB);
    pi_store(outPi, piTB, r0B, tid);
  }
}

extern "C" void kernel_launch(void* const* d_in, const int* in_sizes, int n_in,
                              void* d_out, int out_size, void* d_ws, size_t ws_size,
                              hipStream_t stream) {
  const float* Yh  = (const float*)d_in[0];
  const float* u   = (const float*)d_in[1];
  const float* W1  = (const float*)d_in[2];
  const float* b1  = (const float*)d_in[3];
  const float* W2  = (const float*)d_in[4];
  const float* b2  = (const float*)d_in[5];
  const float* Wa  = (const float*)d_in[6];
  const float* ba  = (const float*)d_in[7];
  const float* Wb  = (const float*)d_in[8];
  const float* bb  = (const float*)d_in[9];
  const float* Wd1 = (const float*)d_in[10];
  const float* bd1 = (const float*)d_in[11];
  const float* Wd2 = (const float*)d_in[12];
  const float* bd2 = (const float*)d_in[13];

  bf16_t* ws   = (bf16_t*)d_ws;
  bf16_t* Wp1  = ws;                  // 6*256*32 = 49152 elems
  bf16_t* Wp2  = Wp1 + 49152;         // 8*256*32 = 65536
  bf16_t* Wpab = Wp2 + 65536;         // 8*64*32  = 16384 (interleaved a/b)
  bf16_t* Wpd1 = Wpab + 16384;        // 1*256*32 = 8192
  bf16_t* Wpd2 = Wpd1 + 8192;         // 8*192*32 = 49152

  float* outRecon = (float*)d_out;
  float* outAlpha = outRecon + (size_t)N_ROWS * D_IN;
  float* outBeta  = outAlpha + (size_t)N_ROWS * K_DIM;
  float* outPi    = outBeta  + (size_t)N_ROWS * K_DIM;

  pack_b_kernel<<<192, 256, 0, stream>>>(W1, Wp1, 162, 256, 256, 6);
  pack_b_kernel<<<256, 256, 0, stream>>>(W2, Wp2, 256, 256, 256, 8);
  pack_ab_kernel<<<64, 256, 0, stream>>>(Wa, Wb, Wpab);
  pack_b_kernel<<<32, 256, 0, stream>>>(Wd1, Wpd1, 30, 256, 256, 1);
  pack_b_kernel<<<192, 256, 0, stream>>>(Wd2, Wpd2, 256, 162, 192, 8);

  usdn_fused<<<N_ROWS / (2 * ROWS), NTHR, 0, stream>>>(Yh, u, b1, b2, ba, bb, bd1, bd2,
                                                       Wp1, Wp2, Wpab, Wpd1, Wpd2,
                                                       outRecon, outAlpha, outBeta, outPi);
}